// Round 1
// 182.757 us; speedup vs baseline: 1.1208x; 1.1208x over previous
//
#include <hip/hip_runtime.h>
#include <hip/hip_bf16.h>

// MDTA: transpose X -> qkv 1x1 conv (MFMA GEMM) -> 3x3 depthwise (LDS) ->
// l2norm(q)+K^T materialize -> flash attention (32x32x16 MFMA, 2 q-tiles x
// 2 K-streams per block, register-resident P via cvt_pk_bf16 + permlane32_swap,
// fixed-max softmax exploiting |q.k|<=1, additive K-split combine) ->
// 1x1 proj (MFMA GEMM).
// Input/output dtype probed at runtime; intermediates bf16 in d_ws.

#define BB 2
#define CCH 192
#define C3 576
#define NH 4
#define HD 48
#define NP 4096

typedef __hip_bfloat16 bf16;
typedef __attribute__((ext_vector_type(8))) short bf16x8;
typedef __attribute__((ext_vector_type(4))) float f32x4;
typedef __attribute__((ext_vector_type(16))) float f32x16;

union I4B8 { int4 i; bf16x8 v; };

__device__ inline float bf2f(bf16 v){ return __bfloat162float(v); }
__device__ inline unsigned short bfbits(bf16 v){ return __builtin_bit_cast(unsigned short, v); }
__device__ inline unsigned short f2bfbits(float f){ return __builtin_bit_cast(unsigned short, __float2bfloat16(f)); }
__device__ inline float bfb2f(short s){ return __uint_as_float(((unsigned)(unsigned short)s)<<16); }

// pack two f32 -> dword of two bf16 (lo = first)
__device__ inline unsigned pkbf(float lo, float hi){
  unsigned r;
  asm("v_cvt_pk_bf16_f32 %0, %1, %2" : "=v"(r) : "v"(lo), "v"(hi));
  return r;
}
// swap lanes 0-31 of x with lanes 32-63 of y (both results used)
__device__ inline void plswap(unsigned &x, unsigned &y){
  asm("v_permlane32_swap_b32 %0, %1" : "+v"(x), "+v"(y));
}

// ---------------------------------------------------------------------------
// Probe input dtype: bf16 data -> low short of each dword has sane exponent.
// ---------------------------------------------------------------------------
__global__ void probe_kernel(const unsigned* __restrict__ x, int* __restrict__ flag)
{
  int t = threadIdx.x;
  unsigned u = x[t];
  int e = (u >> 7) & 0xff;
  int sane = (e >= 100 && e <= 140) || ((u & 0x7fffu) == 0u);
  __shared__ int cnt;
  if (t == 0) cnt = 0;
  __syncthreads();
  if (sane) atomicAdd(&cnt, 1);
  __syncthreads();
  if (t == 0) *flag = (cnt >= 192) ? 1 : 0;
}

// ---------------------------------------------------------------------------
// Convert params to canonical bf16.
// ---------------------------------------------------------------------------
#define NCANON 153988
__global__ __launch_bounds__(256) void convert_params_kernel(
    const int* __restrict__ flag,
    const void* w_qkv, const void* b_qkv, const void* w_dw, const void* b_dw,
    const void* w_proj, const void* b_proj, const void* temp,
    bf16* __restrict__ canon)
{
  const bool isbf = (*flag != 0);
  int i = blockIdx.x*256 + threadIdx.x;
  if (i >= NCANON) return;
  const void* src; int off;
  if      (i < 110592){ src = w_qkv;  off = i; }
  else if (i < 111168){ src = b_qkv;  off = i - 110592; }
  else if (i < 116352){ src = w_dw;   off = i - 111168; }
  else if (i < 116928){ src = b_dw;   off = i - 116352; }
  else if (i < 153792){ src = w_proj; off = i - 116928; }
  else if (i < 153984){ src = b_proj; off = i - 153792; }
  else                { src = temp;   off = i - 153984; }
  float v = isbf ? bf2f(((const bf16*)src)[off]) : ((const float*)src)[off];
  canon[i] = __float2bfloat16(v);
}

// ---------------------------------------------------------------------------
// Transpose X [b][192][4096] (dyn dtype) -> XT [b][4096][192] bf16 bits.
// ---------------------------------------------------------------------------
__global__ __launch_bounds__(256) void transpose_x_kernel(
    const int* __restrict__ flag, const void* __restrict__ Xv,
    short* __restrict__ XT)
{
  const bool isbf = (*flag != 0);
  __shared__ short T[64][66];
  const int c0 = blockIdx.x*64, p0 = blockIdx.y*64, b = blockIdx.z;
  const size_t xbase = (size_t)b*CCH*NP;
  #pragma unroll
  for (int s=0;s<16;s++){
    int i = threadIdx.x + s*256;
    int cc = i>>6, pp = i&63;
    size_t g = xbase + (size_t)(c0+cc)*NP + p0+pp;
    float v = isbf ? bf2f(((const bf16*)Xv)[g]) : ((const float*)Xv)[g];
    T[cc][pp] = (short)f2bfbits(v);
  }
  __syncthreads();
  #pragma unroll
  for (int s=0;s<16;s++){
    int i = threadIdx.x + s*256;
    int pl = i>>6, cl = i&63;
    XT[((size_t)b*NP + p0+pl)*CCH + c0+cl] = T[cl][pl];
  }
}

// ---------------------------------------------------------------------------
// 1x1 conv as MFMA GEMM.  Block 64o x 128p, wave = 32p x 64o.
// ---------------------------------------------------------------------------
__global__ __launch_bounds__(256) void conv1x1_mfma_kernel(
    const int* __restrict__ flag, int ydyn,
    const short* __restrict__ XT,      // [b][4096][192] bf16 bits
    const bf16* __restrict__ Wt,       // [OC][192]
    const bf16* __restrict__ bias,
    void* __restrict__ Yv, int OC)
{
  const bool yf32 = ydyn && (*flag == 0);
  __shared__ __align__(16) short Bs[2][128*32];
  const int tid = threadIdx.x, wave = tid>>6, lane = tid&63;
  const int l16 = lane&15, quad = lane>>4;
  const int o0 = blockIdx.x*64, p0 = blockIdx.y*128, b = blockIdx.z;
  const short* XTb = XT + ((size_t)b*NP + p0)*CCH;
  const short* Wb  = (const short*)Wt;

  f32x4 acc[4][2];
  #pragma unroll
  for (int mt=0;mt<4;mt++){
    #pragma unroll
    for (int r=0;r<4;r++){
      float bv = bf2f(bias[o0+mt*16+quad*4+r]);
      acc[mt][0][r]=bv; acc[mt][1][r]=bv;
    }
  }

  int4 sreg[2];
  I4B8 Afr[2][4];
  #define CLOAD(kc) { _Pragma("unroll") for (int s_=0;s_<2;s_++){ int i_=tid+256*s_; \
      sreg[s_] = *(const int4*)&XTb[(size_t)(i_>>2)*CCH + (kc)*32 + (i_&3)*8]; } }
  #define CSTORE(buf) { _Pragma("unroll") for (int s_=0;s_<2;s_++){ int i_=tid+256*s_; \
      *(int4*)&Bs[buf][(i_>>2)*32 + (i_&3)*8] = sreg[s_]; } }
  #define ALOAD(kc, buf) { _Pragma("unroll") for (int mt_=0;mt_<4;mt_++){ \
      Afr[buf][mt_].i = *(const int4*)&Wb[(size_t)(o0+mt_*16+l16)*CCH + (kc)*32 + quad*8]; } }

  CLOAD(0); CSTORE(0); ALOAD(0,0);
  __syncthreads();

  #pragma unroll
  for (int kc=0; kc<6; kc++){
    const int cur = kc&1;
    if (kc<5){ CLOAD(kc+1); ALOAD(kc+1, cur^1); }
    I4B8 Bf0, Bf1;
    Bf0.i = *(const int4*)&Bs[cur][(wave*32 + l16)*32 + quad*8];
    Bf1.i = *(const int4*)&Bs[cur][(wave*32 + 16 + l16)*32 + quad*8];
    #pragma unroll
    for (int mt=0;mt<4;mt++){
      acc[mt][0] = __builtin_amdgcn_mfma_f32_16x16x32_bf16(Afr[cur][mt].v, Bf0.v, acc[mt][0], 0,0,0);
      acc[mt][1] = __builtin_amdgcn_mfma_f32_16x16x32_bf16(Afr[cur][mt].v, Bf1.v, acc[mt][1], 0,0,0);
    }
    if (kc<5) CSTORE(cur^1);
    __syncthreads();
  }
  #undef CLOAD
  #undef CSTORE
  #undef ALOAD

  #pragma unroll
  for (int mt=0;mt<4;mt++)
    #pragma unroll
    for (int nt=0;nt<2;nt++)
      #pragma unroll
      for (int r=0;r<4;r++){
        int o = o0 + mt*16 + quad*4 + r;
        int p = p0 + wave*32 + nt*16 + l16;
        size_t off = ((size_t)b*OC + o)*NP + p;
        if (yf32) ((float*)Yv)[off] = acc[mt][nt][r];
        else      ((bf16*)Yv)[off]  = __float2bfloat16(acc[mt][nt][r]);
      }
}

// ---------------------------------------------------------------------------
// 3x3 depthwise conv, padding 1. One block per (b,ch) image.
// ---------------------------------------------------------------------------
__global__ __launch_bounds__(256) void dwconv_kernel(
    const bf16* __restrict__ in, const bf16* __restrict__ w,
    const bf16* __restrict__ bias, bf16* __restrict__ out)
{
  __shared__ __align__(16) short img[4096];
  const int bc = blockIdx.x; const int ch = bc % C3;
  const int tid = threadIdx.x;
  const int4* g4 = (const int4*)(in + (size_t)bc*NP);
  int4* s4 = (int4*)img;
  s4[tid] = g4[tid];
  s4[tid+256] = g4[tid+256];
  float wv[9];
  #pragma unroll
  for (int j=0;j<9;j++) wv[j] = bf2f(w[ch*9+j]);
  const float bv = bf2f(bias[ch]);
  __syncthreads();

  const int y = tid>>2, x0 = (tid&3)*16;
  unsigned outw[8];
  #pragma unroll
  for (int j=0;j<16;j++){
    int x = x0+j;
    float s = bv;
    #pragma unroll
    for (int ky=0;ky<3;ky++){
      int yy = y+ky-1; if (yy<0||yy>63) continue;
      const short* rp = &img[yy<<6];
      #pragma unroll
      for (int kx=0;kx<3;kx++){
        int xx = x+kx-1; if (xx<0||xx>63) continue;
        s += wv[ky*3+kx]*bfb2f(rp[xx]);
      }
    }
    unsigned hb = f2bfbits(s);
    if (j&1) outw[j>>1] |= hb<<16; else outw[j>>1] = hb;
  }
  int4* op = (int4*)((short*)out + (size_t)bc*NP + (y<<6) + x0);
  op[0] = *(int4*)&outw[0];
  op[1] = *(int4*)&outw[4];
}

// ---------------------------------------------------------------------------
// L2 normalize q (in place) and k (-> K^T [bh][n][64], zero-padded d 48..63,
// 16B-unit XOR swizzle by n&7).
// ---------------------------------------------------------------------------
__global__ __launch_bounds__(256) void l2norm_t_kernel(
    bf16* __restrict__ buf, short* __restrict__ KT)
{
  int idx = blockIdx.x*256 + threadIdx.x;   // 65536 total
  int n = idx & 4095; int t = idx >> 12;
  int head = t & 3; int qk = (t>>2)&1; int b = t>>3;
  bf16* p = buf + ((size_t)b*C3 + qk*CCH + head*HD)*NP + n;
  float v[HD];
  float ss = 0.f;
  #pragma unroll
  for (int d=0; d<HD; d++){ v[d] = bf2f(p[(size_t)d*NP]); ss += v[d]*v[d]; }
  float inv = 1.0f / fmaxf(sqrtf(ss), 1e-12f);
  if (qk == 0){
    #pragma unroll
    for (int d=0; d<HD; d++) p[(size_t)d*NP] = __float2bfloat16(v[d]*inv);
  } else {
    short* row = KT + ((size_t)(b*NH+head)*NP + n)*64;
    int sw = n & 7;
    #pragma unroll
    for (int u=0; u<8; u++){
      int4 w = {0,0,0,0};
      if (u < 6){
        int d0 = u*8;
        w.x = (unsigned)f2bfbits(v[d0+0]*inv) | ((unsigned)f2bfbits(v[d0+1]*inv)<<16);
        w.y = (unsigned)f2bfbits(v[d0+2]*inv) | ((unsigned)f2bfbits(v[d0+3]*inv)<<16);
        w.z = (unsigned)f2bfbits(v[d0+4]*inv) | ((unsigned)f2bfbits(v[d0+5]*inv)<<16);
        w.w = (unsigned)f2bfbits(v[d0+6]*inv) | ((unsigned)f2bfbits(v[d0+7]*inv)<<16);
      }
      *(int4*)&row[(u^sw)*8] = w;
    }
  }
}

// ---------------------------------------------------------------------------
// Flash attention, mfma_f32_32x32x16_bf16.
// Block = 64 queries x one head; 4 waves = 2 q-tiles(32q) x 2 K-streams(64k
// halves of each staged 128-key chunk). Fixed-max softmax (|q.k|<=1 => p<=1,
// no running max, additive across K-streams). S^T = mfma(K,Q) puts a full
// P-row per lane (q = lane&31); P -> PV A-fragment entirely in registers via
// v_cvt_pk_bf16_f32 + v_permlane32_swap_b32 (no P LDS round-trip).
// Per-wave LDS reads/iter: 6 (K) + 8 (V) b128 vs 32 in the 16x16 version.
// V pad rows 48..63 are never written: garbage there only feeds C columns
// 48..63 which are never stored (per-element containment of MFMA).
// Writes O^T [b][n][192].
// ---------------------------------------------------------------------------
__global__ __launch_bounds__(256) void flash_kernel(
    const bf16* __restrict__ qkv,      // bufB [b][c3][n]
    const short* __restrict__ KT,      // [bh][n][64] swizzled bf16 bits
    const bf16* __restrict__ temp,
    short* __restrict__ OT)            // [b][4096][192] bf16 bits
{
  __shared__ __align__(16) short Ks[2][128*64];   // 32 KB
  __shared__ __align__(16) short Vs[2][64*136];   // 34.8 KB (rows 48..63 pad)

  const int bh = blockIdx.x, b = bh>>2, head = bh&3;
  const int q0 = blockIdx.y * 64;
  const int tid = threadIdx.x, wave = tid>>6, lane = tid&63;
  const int m = lane & 31, h = lane >> 5;
  const int stream = wave >> 1, qtile = wave & 1;

  const short* Vp = (const short*)(qkv + ((size_t)b*C3 + 2*CCH + head*HD)*NP);
  const short* KTs = KT + (size_t)bh*NP*64;
  const float sc = bf2f(temp[head]) * 1.44269504f;
  const float negM = -__builtin_fabsf(sc);       // fixed softmax shift

  // Q B-fragments: B[q=m][d = st*16 + h*8 + j], 3 d-steps cover d 0..47
  I4B8 Qf[3];
  {
    const unsigned short* Qp = (const unsigned short*)(qkv + ((size_t)b*C3 + head*HD)*NP)
                               + q0 + qtile*32 + m;
    #pragma unroll
    for (int st=0; st<3; st++){
      unsigned qb[8];
      #pragma unroll
      for (int j=0;j<8;j++) qb[j] = Qp[(size_t)(st*16 + h*8 + j)*NP];
      Qf[st].i.x = (int)(qb[0] | (qb[1]<<16));
      Qf[st].i.y = (int)(qb[2] | (qb[3]<<16));
      Qf[st].i.z = (int)(qb[4] | (qb[5]<<16));
      Qf[st].i.w = (int)(qb[6] | (qb[7]<<16));
    }
  }

  f32x16 O0, O1;                     // C[q][d]: d-tiles 0..31, 32..63(48..63 dropped)
  #pragma unroll
  for (int r=0;r<16;r++){ O0[r]=0.f; O1[r]=0.f; }
  float rs0 = 0.f, rs1 = 0.f;        // per-lane row-sum partials (q = m)

  int4 kreg[4], vreg[3];
  #define KLOAD(CHUNK) { const int k0_=(CHUNK)<<7; \
    const int4* gk_ = (const int4*)(KTs + (size_t)k0_*64); \
    _Pragma("unroll") for (int s_=0;s_<4;s_++) kreg[s_] = gk_[tid + 256*s_]; \
    _Pragma("unroll") for (int s_=0;s_<3;s_++){ int i_=tid+256*s_; \
      vreg[s_] = *(const int4*)(Vp + (size_t)(i_>>4)*NP + k0_ + (i_&15)*8); } }
  #define KSTORE(BUFI) { int4* lk_ = (int4*)&Ks[BUFI][0]; \
    _Pragma("unroll") for (int s_=0;s_<4;s_++) lk_[tid+256*s_] = kreg[s_]; \
    _Pragma("unroll") for (int s_=0;s_<3;s_++){ int i_=tid+256*s_; \
      *(int4*)&Vs[BUFI][(i_>>4)*136 + (i_&15)*8] = vreg[s_]; } }

  KLOAD(0); KSTORE(0);
  __syncthreads();

  for (int t=0; t<32; ++t){
    const int cur = t & 1;
    if (t < 31) KLOAD(t+1);

    const short* Kb = &Ks[cur][stream*4096];   // this stream's 64-key half
    const short* Vb = &Vs[cur][0];

    #pragma unroll
    for (int kt=0; kt<2; kt++){
      // S^T[kk][q] = mfma(A=K rows kk, B=Q rows q); lane: q=m, kk=(r&3)+8*(r>>2)+4h
      f32x16 S;
      #pragma unroll
      for (int r=0;r<16;r++) S[r] = 0.f;
      #pragma unroll
      for (int st=0; st<3; st++){
        I4B8 A;
        A.i = *(const int4*)&Kb[(kt*32 + m)*64 + (((st*2+h) ^ (lane&7))*8)];
        S = __builtin_amdgcn_mfma_f32_32x32x16_bf16(A.v, Qf[st].v, S, 0,0,0);
      }
      // fixed-max softmax, all in registers
      float p[16];
      #pragma unroll
      for (int r=0;r<16;r++){
        p[r] = __builtin_amdgcn_exp2f(__builtin_fmaf(S[r], sc, negM));
        if (r&1) rs1 += p[r]; else rs0 += p[r];
      }
      // P -> PV A-fragments: cvt_pk pairs + permlane32_swap, 2 k-steps/tile
      #pragma unroll
      for (int ks=0; ks<2; ks++){
        unsigned u0 = pkbf(p[8*ks+0], p[8*ks+1]);   // kk = 16ks+4h+{0,1}
        unsigned u1 = pkbf(p[8*ks+2], p[8*ks+3]);   // kk = 16ks+4h+{2,3}
        unsigned w0 = pkbf(p[8*ks+4], p[8*ks+5]);   // kk = 16ks+8+4h+{0,1}
        unsigned w1 = pkbf(p[8*ks+6], p[8*ks+7]);   // kk = 16ks+8+4h+{2,3}
        plswap(w0, u0);   // -> u0 = A dword0, w0 = A dword2
        plswap(w1, u1);   // -> u1 = A dword1, w1 = A dword3
        I4B8 PA;
        PA.i.x = (int)u0; PA.i.y = (int)u1; PA.i.z = (int)w0; PA.i.w = (int)w1;
        const int kcol = stream*64 + kt*32 + ks*16 + h*8;
        I4B8 BV0, BV1;
        BV0.i = *(const int4*)&Vb[(size_t)m*136 + kcol];
        BV1.i = *(const int4*)&Vb[(size_t)(32+m)*136 + kcol];
        O0 = __builtin_amdgcn_mfma_f32_32x32x16_bf16(PA.v, BV0.v, O0, 0,0,0);
        O1 = __builtin_amdgcn_mfma_f32_32x32x16_bf16(PA.v, BV1.v, O1, 0,0,0);
      }
    }

    if (t < 31) KSTORE(cur^1);
    __syncthreads();
  }
  #undef KLOAD
  #undef KSTORE

  // combine the two K-streams (additive: fixed-max softmax), then normalize
  const float rs = rs0 + rs1;
  float* Cmb = (float*)&Ks[0][0];    // 2*64*33*4 = 16.9 KB, Ks dead
  float* Ls  = (float*)&Vs[0][0];    // per-wave inverse row sums, Vs dead
  if (stream == 1){
    float* dst = Cmb + (qtile*64 + lane)*33;
    #pragma unroll
    for (int r=0;r<16;r++){ dst[r] = O0[r]; dst[16+r] = O1[r]; }
    dst[32] = rs;
  }
  __syncthreads();
  if (stream == 0){
    const float* src = Cmb + (qtile*64 + lane)*33;
    #pragma unroll
    for (int r=0;r<16;r++){ O0[r] += src[r]; O1[r] += src[16+r]; }
    float rt = rs + src[32];
    rt += __shfl_xor(rt, 32);                 // fold the two h-halves
    if (lane < 32) Ls[qtile*32 + lane] = 1.0f / rt;
    #pragma unroll
    for (int r=0;r<16;r++){
      const int qr = (r&3) + 8*(r>>2) + 4*h;
      const float inv = Ls[qtile*32 + qr];
      short* row = OT + ((size_t)b*NP + q0 + qtile*32 + qr)*CCH + head*HD;
      row[m] = (short)f2bfbits(O0[r]*inv);
      if (m < 16) row[32+m] = (short)f2bfbits(O1[r]*inv);
    }
  }
}

// ---------------------------------------------------------------------------
extern "C" void kernel_launch(void* const* d_in, const int* in_sizes, int n_in,
                              void* d_out, int out_size, void* d_ws, size_t ws_size,
                              hipStream_t stream)
{
  // ws layout (bytes) — 19.2 MB footprint proven since R3:
  //   [0]        int flag
  //   [16]       bf16 canon[153988]
  //   [308096]   bf16 bufA[2*576*4096]  (O^T head; K^T at el 1572864)
  //   [9745280]  bf16 bufB[2*576*4096]  (X^T borrows head pre-dwconv)
  int*  flag  = (int*)d_ws;
  bf16* canon = (bf16*)((char*)d_ws + 16);
  bf16* bufA  = (bf16*)((char*)d_ws + 308096);
  bf16* bufB  = (bf16*)((char*)d_ws + 9745280);
  short* XT = (short*)bufB;
  short* OT = (short*)bufA;
  short* KT = (short*)(bufA + 1572864);

  bf16* cw_qkv  = canon;
  bf16* cb_qkv  = canon + 110592;
  bf16* cw_dw   = canon + 111168;
  bf16* cb_dw   = canon + 116352;
  bf16* cw_proj = canon + 116928;
  bf16* cb_proj = canon + 153792;
  bf16* ctemp   = canon + 153984;

  probe_kernel<<<1, 256, 0, stream>>>((const unsigned*)d_in[0], flag);
  convert_params_kernel<<<602, 256, 0, stream>>>(flag,
      d_in[1], d_in[2], d_in[3], d_in[4], d_in[5], d_in[6], d_in[7], canon);
  transpose_x_kernel<<<dim3(3,64,2), 256, 0, stream>>>(flag, d_in[0], XT);
  conv1x1_mfma_kernel<<<dim3(9,32,2), 256, 0, stream>>>(flag, 0,
      XT, cw_qkv, cb_qkv, bufA, C3);
  dwconv_kernel<<<dim3(BB*C3), 256, 0, stream>>>(bufA, cw_dw, cb_dw, bufB);
  l2norm_t_kernel<<<dim3(256), 256, 0, stream>>>(bufB, KT);
  flash_kernel<<<dim3(8,64), 256, 0, stream>>>(bufB, KT, ctemp, OT);
  conv1x1_mfma_kernel<<<dim3(3,32,2), 256, 0, stream>>>(flag, 1,
      OT, cw_proj, cb_proj, d_out, CCH);
}